// Round 11
// baseline (21.027 us; speedup 1.0000x reference)
//
#include <hip/hip_runtime.h>

#define BB 16
#define NN 2048
#define NFF 512
#define DD 4
#define BN (BB * NN)   // 32768

#define RS   80        // K-rows per slice (stacked [T;FF] rows: 2560 = 32*80)
#define NSL  32        // slices -> grid.y
#define WRR  20        // rows per wave (4 waves x 20 = 80)
#define JC   256       // columns per x-block (64 lanes x 4 cols, float4)
#define NX   (NN / JC) // 8 column groups; NX*NSL = 256 blocks = 1/CU

// ---------------- Kernel A: balanced stacked GEMV ----------------
// Stacked operand OP[b,i], i in [0,2560): i<2048 -> T (computed from Xbuf/stp),
// else FF[i-2048]. Stacked W: row i<2048 -> Wint[i], else Wff[i-2048].
// part[s][b][j] = sum_{i in slice s} OP[b,i]*W[i,j]   (32 slices of 80 rows)
// x==0 blocks write scal_part[s][4][16] = per-slice (c1,c2,c3,c4) partials.
__global__ __launch_bounds__(256) void snn_gemv(
    const float* __restrict__ Wint, const float* __restrict__ Wff,
    const float* __restrict__ Xbuf, const float* __restrict__ stp,
    const float* __restrict__ FF,
    const float* __restrict__ xpre_int, const float* __restrict__ xpre_ff,
    float* __restrict__ part, float* __restrict__ scal_part)
{
    __shared__ __align__(16) float c_lds[BB * RS];     // 5 KB  [b][row]
    __shared__ float4 red[2 * BB * 64];                // 32 KB [buf][b][lane]
    int x = blockIdx.x, s = blockIdx.y;
    int t = threadIdx.x;
    int w = t >> 6, l = t & 63;
    int g0 = s * RS;                                   // first stacked row

    // ---- staging: 1280 elems, e -> (b = e/80, row = e%80); consecutive e
    // within one b are consecutive global addresses (coalesced runs of 320B)
    #pragma unroll
    for (int k = 0; k < 5; ++k) {
        int e = k * 256 + t;
        int b = e / RS, row = e - b * RS;
        int grow = g0 + row;
        float val;
        if (grow < NN) {
            int base = b * NN + grow;
            float acc = 0.f;
            #pragma unroll
            for (int d = 0; d < DD; ++d) {
                float xd = Xbuf[d * BN + base];
                float sv = stp[d * BN + base];
                acc += xd * (1.f + 0.95f * sv - 0.3f * xd);
            }
            val = acc;
        } else {
            val = FF[b * NFF + grow - NN];
        }
        c_lds[b * RS + row] = val;
    }
    __syncthreads();

    // ---- scal partials (x==0 blocks only): rows l and 64+l per b
    if (x == 0) {
        #pragma unroll
        for (int bb = 0; bb < 4; ++bb) {
            int b = w * 4 + bb;
            float s0i = 0.f, s1i = 0.f, s0f = 0.f, s1f = 0.f;
            {
                int row = l, grow = g0 + row;
                float tv = c_lds[b * RS + row];
                if (grow < NN) {
                    s0i = tv * xpre_int[b * NN + grow];
                    s1i = tv * Xbuf[b * NN + grow];          // Xd0
                } else {
                    s0f = tv * xpre_ff[b * NFF + grow - NN];
                    s1f = tv * tv;
                }
            }
            if (l < RS - 64) {
                int row = 64 + l, grow = g0 + row;
                float tv = c_lds[b * RS + row];
                if (grow < NN) {
                    s0i += tv * xpre_int[b * NN + grow];
                    s1i += tv * Xbuf[b * NN + grow];
                } else {
                    s0f += tv * xpre_ff[b * NFF + grow - NN];
                    s1f += tv * tv;
                }
            }
            #pragma unroll
            for (int o = 32; o; o >>= 1) {
                s0i += __shfl_xor(s0i, o); s1i += __shfl_xor(s1i, o);
                s0f += __shfl_xor(s0f, o); s1f += __shfl_xor(s1f, o);
            }
            if (l == 0) {
                scal_part[s * 64 + 0 * BB + b] = s0i;
                scal_part[s * 64 + 1 * BB + b] = s1i;
                scal_part[s * 64 + 2 * BB + b] = s0f;
                scal_part[s * 64 + 3 * BB + b] = s1f;
            }
        }
    }

    int j0 = x * JC + l * 4;

    // ---- issue ALL 20 row loads up front (wave-uniform row->matrix select)
    float4 buf[WRR];
    #pragma unroll
    for (int r = 0; r < WRR; ++r) {
        int grow = g0 + w * WRR + r;
        const float* src = (grow < NN) ? (Wint + (size_t)grow * NN)
                                       : (Wff + (size_t)(grow - NN) * NN);
        buf[r] = *(const float4*)(src + j0);
    }

    float4 acc[BB];
    #pragma unroll
    for (int b = 0; b < BB; ++b) acc[b] = make_float4(0.f, 0.f, 0.f, 0.f);

    // ---- 4 rows per step; c_lds read is a float4 broadcast
    #pragma unroll
    for (int rg = 0; rg < 5; ++rg) {
        float4 wv0 = buf[rg * 4 + 0], wv1 = buf[rg * 4 + 1];
        float4 wv2 = buf[rg * 4 + 2], wv3 = buf[rg * 4 + 3];
        int base = w * WRR + rg * 4;
#define FMA16(b) { \
        float4 cr = *(const float4*)&c_lds[(b) * RS + base]; \
        acc[b].x += cr.x * wv0.x + cr.y * wv1.x + cr.z * wv2.x + cr.w * wv3.x; \
        acc[b].y += cr.x * wv0.y + cr.y * wv1.y + cr.z * wv2.y + cr.w * wv3.y; \
        acc[b].z += cr.x * wv0.z + cr.y * wv1.z + cr.z * wv2.z + cr.w * wv3.z; \
        acc[b].w += cr.x * wv0.w + cr.y * wv1.w + cr.z * wv2.w + cr.w * wv3.w; }
        FMA16(0)  FMA16(1)  FMA16(2)  FMA16(3)
        FMA16(4)  FMA16(5)  FMA16(6)  FMA16(7)
        FMA16(8)  FMA16(9)  FMA16(10) FMA16(11)
        FMA16(12) FMA16(13) FMA16(14) FMA16(15)
#undef FMA16
    }

    // ---- tree-reduce 4 waves: [b][lane] float4, contiguous b128 ops
    if (w >= 2) {
        float4* rb = &red[(w - 2) * BB * 64];
        #pragma unroll
        for (int b = 0; b < BB; ++b) rb[b * 64 + l] = acc[b];
    }
    __syncthreads();
    if (w < 2) {
        const float4* rb = &red[w * BB * 64];
        #pragma unroll
        for (int b = 0; b < BB; ++b) {
            float4 v = rb[b * 64 + l];
            acc[b].x += v.x; acc[b].y += v.y; acc[b].z += v.z; acc[b].w += v.w;
        }
    }
    __syncthreads();
    if (w == 1) {
        #pragma unroll
        for (int b = 0; b < BB; ++b) red[b * 64 + l] = acc[b];
    }
    __syncthreads();
    if (w == 0) {
        float* pp = part + (size_t)s * BN + j0;
        #pragma unroll
        for (int b = 0; b < BB; ++b) {
            float4 v = red[b * 64 + l];
            acc[b].x += v.x; acc[b].y += v.y; acc[b].z += v.z; acc[b].w += v.w;
            *(float4*)(pp + (size_t)b * NN) = acc[b];
        }
    }
}

// ---------------- Kernel B: X + reduce partials + finalize ----------------
__global__ __launch_bounds__(256) void snn_post(
    const float* __restrict__ V, const float* __restrict__ th,
    const float* __restrict__ xpost,
    const float* __restrict__ part, const float* __restrict__ scal_part,
    float* __restrict__ out_X, float* __restrict__ out_V)
{
    int idx = blockIdx.x * 256 + threadIdx.x;
    int b = idx >> 11;                   // block-uniform
    float c1 = 0.f, c2 = 0.f, c3 = 0.f, c4 = 0.f;
    #pragma unroll
    for (int s = 0; s < NSL; ++s) {
        c1 += scal_part[s * 64 + 0 * BB + b];
        c2 += scal_part[s * 64 + 1 * BB + b];
        c3 += scal_part[s * 64 + 2 * BB + b];
        c4 += scal_part[s * 64 + 3 * BB + b];
    }
    float v = V[idx];
    float x = 1.f / (1.f + expf(-(v - 1.f - th[idx]) * 5.f));
    out_X[idx] = x;
    float sum = 0.f;
    #pragma unroll
    for (int s = 0; s < NSL; ++s) sum += part[(size_t)s * BN + idx];
    float c = sum + 0.01f * (c1 + c3) * x - 0.012f * (c2 + c4) * xpost[idx];
    out_V[idx] = 0.9f * v * (1.f - x) + c;
}

extern "C" void kernel_launch(void* const* d_in, const int* in_sizes, int n_in,
                              void* d_out, int out_size, void* d_ws, size_t ws_size,
                              hipStream_t stream) {
    const float* FF       = (const float*)d_in[0];
    const float* V        = (const float*)d_in[1];
    const float* th       = (const float*)d_in[2];
    const float* Xbuf     = (const float*)d_in[3];
    const float* stp      = (const float*)d_in[4];
    const float* xpre_int = (const float*)d_in[5];
    const float* xpost    = (const float*)d_in[6];
    const float* xpre_ff  = (const float*)d_in[7];
    const float* Wint     = (const float*)d_in[8];
    const float* Wff      = (const float*)d_in[9];
    float* out = (float*)d_out;
    float* ws  = (float*)d_ws;

    float* part = ws;                    // 32 * 32768 floats (plain stores)
    float* sp   = ws + NSL * BN;         // 32*64 floats (plain stores)

    snn_gemv<<<dim3(NX, NSL), 256, 0, stream>>>(
        Wint, Wff, Xbuf, stp, FF, xpre_int, xpre_ff, part, sp);

    snn_post<<<BN / 256, 256, 0, stream>>>(
        V, th, xpost, part, sp, out, out + BN);
}